// Round 6
// baseline (94.517 us; speedup 1.0000x reference)
//
#include <hip/hip_runtime.h>

#define BB 2
#define HH 16
#define SS 2048
#define DMODEL 1024

typedef unsigned short ushort_t;
typedef short bf16x8 __attribute__((ext_vector_type(8)));   // 8 bf16 = 4 VGPR
typedef float f32x4 __attribute__((ext_vector_type(4)));

__device__ __forceinline__ unsigned short f2bf(float f) {
  union { float f; unsigned int u; } x; x.f = f;
  unsigned int u = x.u;
  return (unsigned short)((u + 0x7fffu + ((u >> 16) & 1u)) >> 16);  // RNE
}
__device__ __forceinline__ unsigned int pack2(float a, float b) {
  return (unsigned int)f2bf(a) | ((unsigned int)f2bf(b) << 16);
}
// 2 f32 -> packed 2x bf16 in one instruction (gfx950; no builtin, T12 recipe)
__device__ __forceinline__ unsigned int cvtpk(float lo, float hi) {
  unsigned int r;
  asm("v_cvt_pk_bf16_f32 %0, %1, %2" : "=v"(r) : "v"(lo), "v"(hi));
  return r;
}
// async global->LDS, 16B per lane; LDS dest is wave-uniform base + lane*16
__device__ __forceinline__ void gload16(const ushort_t* g, ushort_t* l) {
  __builtin_amdgcn_global_load_lds(
      (const __attribute__((address_space(1))) void*)g,
      (__attribute__((address_space(3))) void*)l, 16, 0, 0);
}

// ---------------------------------------------------------------------------
// fp32 [B,S,H*64] -> bf16 Qh (pre-scaled by log2(e)/8), Kh [B,H,S,64];
// V -> Vt [B,H,64,S] with per-64-tile k-permutation matching attn's in-lane
// P layout (swapped-QK): Vt[d][64t + pi(m)] = V[64t + m][d],
// pi(c*16+g*4+r) = (c>>1)*32 + g*8 + (c&1)*4 + r.
// ---------------------------------------------------------------------------
__global__ void __launch_bounds__(256)
conv_qkv(const float* __restrict__ q, const float* __restrict__ k,
         const float* __restrict__ v, ushort_t* __restrict__ Qh,
         ushort_t* __restrict__ Kh, ushort_t* __restrict__ Vt) {
  const float c_sc = 0.18033688011112042f;  // log2(e)/sqrt(64): folded into Q
  __shared__ float vlds[64][65];  // +1 pad: conflict-free column reads
  int bh = blockIdx.y;
  int b = bh >> 4, h = bh & 15;
  int s0 = blockIdx.x * 64;
  int t = threadIdx.x;
#pragma unroll
  for (int j = 0; j < 4; ++j) {
    int idx = t + j * 256;
    int r = idx >> 4, c4 = idx & 15;  // 64 s-rows x 16 float4 of the 64-wide head slice
    size_t in_off = ((size_t)(b * SS + s0 + r)) * DMODEL + h * 64 + c4 * 4;
    float4 qa = *(const float4*)(q + in_off);
    float4 ka = *(const float4*)(k + in_off);
    float4 va = *(const float4*)(v + in_off);
    size_t out_off = ((size_t)bh * SS + s0 + r) * 64 + c4 * 4;
    *(uint2*)(Qh + out_off) = make_uint2(pack2(qa.x * c_sc, qa.y * c_sc),
                                         pack2(qa.z * c_sc, qa.w * c_sc));
    *(uint2*)(Kh + out_off) = make_uint2(pack2(ka.x, ka.y), pack2(ka.z, ka.w));
    vlds[r][c4 * 4 + 0] = va.x;
    vlds[r][c4 * 4 + 1] = va.y;
    vlds[r][c4 * 4 + 2] = va.z;
    vlds[r][c4 * 4 + 3] = va.w;
  }
  __syncthreads();
#pragma unroll
  for (int j = 0; j < 4; ++j) {
    int idx = t + j * 256;
    int d = idx >> 4, u = idx & 15;  // 64 d-rows x 16 chunks of 4 permuted-k
    // chunk u covers positions u*4..u*4+3  <-  orig rows m0..m0+3,
    // m0 = c*16 + g*4 with c = (u>>3)*2 + (u&1), g = (u>>1)&3.
    int c = ((u >> 3) << 1) | (u & 1);
    int g = (u >> 1) & 3;
    int m0 = c * 16 + g * 4;
    size_t voff = ((size_t)bh * 64 + d) * SS + s0 + u * 4;
    *(uint2*)(Vt + voff) =
        make_uint2(pack2(vlds[m0 + 0][d], vlds[m0 + 1][d]),
                   pack2(vlds[m0 + 2][d], vlds[m0 + 3][d]));
  }
}

// fp32 [1024,1024] -> bf16 same layout (rows of W == B^T-GEMM operand rows)
__global__ void __launch_bounds__(256)
conv_w(const float* __restrict__ w, ushort_t* __restrict__ wb) {
  int i = blockIdx.x * 256 + threadIdx.x;  // one thread per 8 elements
  float4 a = *(const float4*)(w + (size_t)i * 8);
  float4 b = *(const float4*)(w + (size_t)i * 8 + 4);
  uint4 o;
  o.x = pack2(a.x, a.y);
  o.y = pack2(a.z, a.w);
  o.z = pack2(b.x, b.y);
  o.w = pack2(b.z, b.w);
  *(uint4*)(wb + (size_t)i * 8) = o;
}

// ---------------------------------------------------------------------------
// Flash attention fwd, no-max online softmax. 4 waves/block, KV tile 64,
// K/V staged once/block via global_load_lds (2-phase dbuf, pre-swizzled src).
// R5: 64 q-rows/wave (qb=4, q-tile 256/block, grid 256 = 1 block/CU) —
// halves the per-q-row K/V ds_read + staging tax (R4 analysis: LDS pipe ~45%,
// all 4 waves read identical fragments). l computed by MFMA-with-ones
// (lands in o's C-layout: no epilogue transpose, no VALU adds). Literal
// buffer index via 2x unroll -> ds addresses fold to base+imm.
// ---------------------------------------------------------------------------
__global__ void __launch_bounds__(256, 1)
attn_fwd(const ushort_t* __restrict__ Qh, const ushort_t* __restrict__ Kh,
         const ushort_t* __restrict__ Vt, ushort_t* __restrict__ ctx) {
  __shared__ ushort_t K_lds[2][64][64];   // 8KB per buf, linear (row=kv, col=d)
  __shared__ ushort_t V_lds[2][64][64];   // 8KB per buf (row=d, col=perm-kv)
  int bh = blockIdx.y;
  int q0 = blockIdx.x * 256;
  int wid = threadIdx.x >> 6;
  int lane = threadIdx.x & 63;
  int g = lane >> 4, lr = lane & 15;
  int rsub = lane >> 3, ch = (lane & 7) ^ rsub;  // stage: row-in-8 / swizzled chunk

  const ushort_t* Qp = Qh + (size_t)bh * SS * 64;
  const ushort_t* Kp = Kh + (size_t)bh * SS * 64;
  const ushort_t* Vp = Vt + (size_t)bh * 64 * SS;

  // Q fragments held in registers for the whole kernel (64 rows/wave).
  // Serves as B-operand of mfma(K,Q): B[d][q]=Q[q][d].
  bf16x8 qf[4][2];
#pragma unroll
  for (int qb = 0; qb < 4; ++qb) {
    int row = q0 + wid * 64 + qb * 16 + lr;
#pragma unroll
    for (int kk = 0; kk < 2; ++kk)
      qf[qb][kk] = *(const bf16x8*)(Qp + (size_t)row * 64 + kk * 32 + g * 8);
  }

  const f32x4 vzero = {0.f, 0.f, 0.f, 0.f};
  const short ob = (short)0x3F80;  // bf16 1.0
  const bf16x8 ones = {ob, ob, ob, ob, ob, ob, ob, ob};
  f32x4 o[4][4];
  f32x4 ol[4];  // l accumulator via mfma(P, ones): row=g*4+r = q, cols equal
#pragma unroll
  for (int qb = 0; qb < 4; ++qb) {
    ol[qb] = vzero;
#pragma unroll
    for (int d = 0; d < 4; ++d) o[qb][d] = vzero;
  }

  // Stage one 64-kv tile: wave w loads rows [w*8,+8) and [32+w*8,+8) of
  // K and V^T. Global chunk pre-swizzled: LDS[row][c] = G[row][c ^ (row&7)].
  auto stage = [&](int buf, int kv) {
#pragma unroll
    for (int j = 0; j < 2; ++j) {
      int i = j * 4 + wid;
      gload16(Kp + (size_t)(kv + i * 8 + rsub) * 64 + ch * 8, &K_lds[buf][i * 8][0]);
      gload16(Vp + (size_t)(i * 8 + rsub) * SS + kv + ch * 8, &V_lds[buf][i * 8][0]);
    }
  };

  const int NT = SS / 64;
  auto tile = [&](int cur, int t) {  // cur is a LITERAL at each call site
    if (t + 1 < NT) stage(cur ^ 1, (t + 1) * 64);  // in flight during compute

    // K/V fragments (swizzled read): logical [c*16+lr][kk*32+g*8..+8)
    bf16x8 kf[4][2], vf[4][2];
#pragma unroll
    for (int c = 0; c < 4; ++c)
#pragma unroll
      for (int kk = 0; kk < 2; ++kk) {
        kf[c][kk] = *(const bf16x8*)&K_lds[cur][c * 16 + lr]
                                          [((kk * 4 + g) ^ (lr & 7)) * 8];
        vf[c][kk] = *(const bf16x8*)&V_lds[cur][c * 16 + lr]
                                          [((kk * 4 + g) ^ (lr & 7)) * 8];
      }

#pragma unroll
    for (int qb = 0; qb < 4; ++qb) {
      // S^T = K·Q^T: lane holds s[c][r] = S[k=c*16+g*4+r][q=qb*16+lr]
      f32x4 s[4];
      __builtin_amdgcn_s_setprio(1);
#pragma unroll
      for (int c = 0; c < 4; ++c) {
        s[c] = __builtin_amdgcn_mfma_f32_16x16x32_bf16(kf[c][0], qf[qb][0], vzero, 0, 0, 0);
        s[c] = __builtin_amdgcn_mfma_f32_16x16x32_bf16(kf[c][1], qf[qb][1], s[c], 0, 0, 0);
      }
      __builtin_amdgcn_s_setprio(0);
      // exp (Q pre-scaled) + pack to PV A-fragments.
      float p[4][4];
#pragma unroll
      for (int c = 0; c < 4; ++c)
#pragma unroll
        for (int r = 0; r < 4; ++r) p[c][r] = __builtin_amdgcn_exp2f(s[c][r]);
      // pf[kk] elem j: (c,r) = (kk*2+(j>>2), j&3)  [pi-permutation, V matches]
      bf16x8 pf[2];
#pragma unroll
      for (int kk = 0; kk < 2; ++kk) {
        uint4 w;
        w.x = cvtpk(p[kk * 2][0], p[kk * 2][1]);
        w.y = cvtpk(p[kk * 2][2], p[kk * 2][3]);
        w.z = cvtpk(p[kk * 2 + 1][0], p[kk * 2 + 1][1]);
        w.w = cvtpk(p[kk * 2 + 1][2], p[kk * 2 + 1][3]);
        pf[kk] = *(bf16x8*)&w;
      }
      // PV + l: o += P·V_perm ; ol += P·1  (same C-layout as o)
      __builtin_amdgcn_s_setprio(1);
      ol[qb] = __builtin_amdgcn_mfma_f32_16x16x32_bf16(pf[0], ones, ol[qb], 0, 0, 0);
      ol[qb] = __builtin_amdgcn_mfma_f32_16x16x32_bf16(pf[1], ones, ol[qb], 0, 0, 0);
#pragma unroll
      for (int d = 0; d < 4; ++d) {
        o[qb][d] = __builtin_amdgcn_mfma_f32_16x16x32_bf16(pf[0], vf[d][0], o[qb][d], 0, 0, 0);
        o[qb][d] = __builtin_amdgcn_mfma_f32_16x16x32_bf16(pf[1], vf[d][1], o[qb][d], 0, 0, 0);
      }
      __builtin_amdgcn_s_setprio(0);
    }
    // all waves done with buf[cur]; staged buf[cur^1] drained at the barrier
    __syncthreads();
  };

  stage(0, 0);
  __syncthreads();  // drains vmcnt: buf0 ready
#pragma unroll 1
  for (int t = 0; t < NT; t += 2) {
    tile(0, t);      // literal buffer indices: ds addrs = base + imm offset
    tile(1, t + 1);
  }

  // ol[qb][r] = l for q-row g*4+r (all cols equal) — direct reciprocal.
  int b = bh >> 4, h = bh & 15;
#pragma unroll
  for (int qb = 0; qb < 4; ++qb) {
    float linv[4];
#pragma unroll
    for (int r = 0; r < 4; ++r) linv[r] = __builtin_amdgcn_rcpf(ol[qb][r]);
#pragma unroll
    for (int d = 0; d < 4; ++d)
#pragma unroll
      for (int r = 0; r < 4; ++r) {
        size_t row = (size_t)b * SS + q0 + wid * 64 + qb * 16 + g * 4 + r;
        ctx[row * DMODEL + h * 64 + d * 16 + lr] = f2bf(o[qb][d][r] * linv[r]);
      }
  }
}

// ---------------------------------------------------------------------------
// out[4096,1024] fp32 = ctx_bf16[4096,1024] @ Wb^T   (B^T-layout GEMM)
// 128x128 tile, BK=64, 4 waves of 64x64. R5: global_load_lds w=16 staging
// (pre-swizzled source, linear LDS, swizzled b128 reads) + 2-phase dbuf —
// same idiom as attn_fwd's stage().
// ---------------------------------------------------------------------------
__global__ void __launch_bounds__(256)
proj_gemm(const ushort_t* __restrict__ A, const ushort_t* __restrict__ Bw,
          float* __restrict__ out) {
  __shared__ ushort_t At[2][128][64];
  __shared__ ushort_t Bt[2][128][64];
  int m0 = blockIdx.x * 128, n0 = blockIdx.y * 128;
  int t = threadIdx.x;
  int wid = t >> 6, lane = t & 63;
  int wr = wid >> 1, wc = wid & 1;
  int g = lane >> 4, lr = lane & 15;
  int rsub = lane >> 3, ch = (lane & 7) ^ rsub;
  const f32x4 vzero = {0.f, 0.f, 0.f, 0.f};
  f32x4 acc[4][4];
#pragma unroll
  for (int m = 0; m < 4; ++m)
#pragma unroll
    for (int n = 0; n < 4; ++n) acc[m][n] = vzero;

  auto stage = [&](int buf, int k0) {
#pragma unroll
    for (int j = 0; j < 4; ++j) {
      int i = j * 4 + wid;  // 16 row-groups of 8 rows
      gload16(A + (size_t)(m0 + i * 8 + rsub) * DMODEL + k0 + ch * 8, &At[buf][i * 8][0]);
      gload16(Bw + (size_t)(n0 + i * 8 + rsub) * DMODEL + k0 + ch * 8, &Bt[buf][i * 8][0]);
    }
  };

  const int NTK = DMODEL / 64;  // 16
  auto step = [&](int cur, int kt) {
    if (kt + 1 < NTK) stage(cur ^ 1, (kt + 1) * 64);
#pragma unroll
    for (int kk = 0; kk < 2; ++kk) {
      bf16x8 af[4], bf[4];
#pragma unroll
      for (int m = 0; m < 4; ++m)
        af[m] = *(const bf16x8*)&At[cur][wr * 64 + m * 16 + lr]
                                      [((kk * 4 + g) ^ (lr & 7)) * 8];
#pragma unroll
      for (int n = 0; n < 4; ++n)
        bf[n] = *(const bf16x8*)&Bt[cur][wc * 64 + n * 16 + lr]
                                      [((kk * 4 + g) ^ (lr & 7)) * 8];
#pragma unroll
      for (int m = 0; m < 4; ++m)
#pragma unroll
        for (int n = 0; n < 4; ++n)
          acc[m][n] = __builtin_amdgcn_mfma_f32_16x16x32_bf16(af[m], bf[n], acc[m][n], 0, 0, 0);
    }
    __syncthreads();
  };

  stage(0, 0);
  __syncthreads();
#pragma unroll 1
  for (int kt = 0; kt < NTK; kt += 2) {
    step(0, kt);
    step(1, kt + 1);
  }
#pragma unroll
  for (int m = 0; m < 4; ++m)
#pragma unroll
    for (int n = 0; n < 4; ++n)
#pragma unroll
      for (int r = 0; r < 4; ++r)
        out[(size_t)(m0 + wr * 64 + m * 16 + g * 4 + r) * DMODEL +
            n0 + wc * 64 + n * 16 + lr] = acc[m][n][r];
}

extern "C" void kernel_launch(void* const* d_in, const int* in_sizes, int n_in,
                              void* d_out, int out_size, void* d_ws, size_t ws_size,
                              hipStream_t stream) {
  const float* q = (const float*)d_in[0];
  const float* k = (const float*)d_in[1];
  const float* v = (const float*)d_in[2];
  const float* w = (const float*)d_in[3];
  float* out = (float*)d_out;

  size_t nqk = (size_t)BB * HH * SS * 64;  // 4,194,304 elems per tensor
  ushort_t* Qh = (ushort_t*)d_ws;
  ushort_t* Kh = Qh + nqk;
  ushort_t* Vt = Kh + nqk;
  ushort_t* ctx = Vt + nqk;
  ushort_t* Wb = ctx + (size_t)BB * SS * DMODEL;
  size_t need = (4 * nqk + (size_t)DMODEL * DMODEL) * sizeof(ushort_t);  // ~34 MB
  if (ws_size < need) return;

  conv_qkv<<<dim3(SS / 64, BB * HH), 256, 0, stream>>>(q, k, v, Qh, Kh, Vt);
  conv_w<<<(DMODEL * DMODEL / 8) / 256, 256, 0, stream>>>(w, Wb);
  attn_fwd<<<dim3(SS / 256, BB * HH), 256, 0, stream>>>(Qh, Kh, Vt, ctx);
  proj_gemm<<<dim3((BB * SS) / 128, DMODEL / 128), 256, 0, stream>>>(ctx, Wb, out);
}